// Round 11
// baseline (1455.267 us; speedup 1.0000x reference)
//
#include <hip/hip_runtime.h>
#include <hip/hip_bf16.h>
#include <stdint.h>

#define NPTS   131072
#define NFEAT  256
#define NCLUST 1024

#define BM 64
#define BNC 128
#define NCHUNK (NCLUST / BNC)   // 8
#define BK 64
#define CAND_CAP 32
#define MARGIN 16.0f
#define SBIAS 1024.0f

typedef unsigned short u16;
typedef unsigned int u32;
typedef __attribute__((ext_vector_type(8))) short bf16x8;
typedef __attribute__((ext_vector_type(4))) float f32x4;
typedef __attribute__((ext_vector_type(8))) u16 u16x8;

__device__ inline u16 f2bf(float f) {
    union { float f; u32 u; } v; v.f = f;
    u32 u = v.u;
    u32 r = (u + 0x7FFFu + ((u >> 16) & 1u)) >> 16;  // RNE, no NaN in this data
    return (u16)r;
}

#define GL2LDS(g, l) __builtin_amdgcn_global_load_lds( \
    (const __attribute__((address_space(1))) void*)(g), \
    (__attribute__((address_space(3))) void*)(l), 16, 0, 0)

// ---------------- K1: fp32 -> bf16 (8 elems/thread); used for both x and centers ----------
__global__ void prep_bf16(const float* __restrict__ in, u16* __restrict__ outbf) {
    const size_t i = (size_t)blockIdx.x * 256 + threadIdx.x;
    const float4* xv = (const float4*)in + i * 2;
    float4 a = xv[0], b = xv[1];
    u16x8 o;
    o[0] = f2bf(a.x); o[1] = f2bf(a.y); o[2] = f2bf(a.z); o[3] = f2bf(a.w);
    o[4] = f2bf(b.x); o[5] = f2bf(b.y); o[6] = f2bf(b.z); o[7] = f2bf(b.w);
    ((u16x8*)outbf)[i] = o;
}

// ---------------- K2: numpy-AVX512-replicated sum of squares per 256-row ----------------
// numpy pairwise_sum_FLOAT, NPY_SIMD path ("8 times unroll ... allows vectorization
// with avx without changing summation ordering"), AVX512 vstep=16: n=256 splits
// 128+128. Each 128-block: 8 vector accumulators r[j][l] = t[16j+l] (single round:
// 8*16 == 128), vector-combined v = ((r0+r1)+(r2+r3))+((r4+r5)+(r6+r7)), then
// npyv_sum_f32 = _mm512_reduce_add_ps lane-halving: u[l]=v[l]+v[l+8];
// w[l]=u[l]+u[l+4]; y0=w0+w2, y1=w1+w3; s=y0+y1.
// t[i] = a[i]*a[i] rounded first (numpy materializes x*x as a temp); contract(off)
// keeps that rounding (no fma fusion). ulp(c2~256)=3e-5 > sqrt-collapse window 2.1e-5,
// so this tree must be ulp-exact for near-tie label decisions.
__device__ __forceinline__ float np_sq_sum256(const float* __restrict__ row) {
    #pragma clang fp contract(off)
    float s[2];
    #pragma unroll
    for (int h = 0; h < 2; ++h) {
        const float* a = row + h * 128;
        float v[16];
        #pragma unroll
        for (int l = 0; l < 16; ++l) {
            float q[8];
            #pragma unroll
            for (int j = 0; j < 8; ++j) { float e = a[16 * j + l]; q[j] = e * e; }
            v[l] = ((q[0] + q[1]) + (q[2] + q[3])) + ((q[4] + q[5]) + (q[6] + q[7]));
        }
        float u[8];
        #pragma unroll
        for (int l = 0; l < 8; ++l) u[l] = v[l] + v[l + 8];
        float w4[4];
        #pragma unroll
        for (int l = 0; l < 4; ++l) w4[l] = u[l] + u[l + 4];
        float y0 = w4[0] + w4[2], y1 = w4[1] + w4[3];
        s[h] = y0 + y1;
    }
    return s[0] + s[1];
}

__global__ void np_row_sq(const float* __restrict__ m, float* __restrict__ out, int nrows) {
    int r = blockIdx.x * 256 + threadIdx.x;
    if (r < nrows) out[r] = np_sq_sum256(m + (size_t)r * NFEAT);
}

// ---------------- K3: bf16 MFMA GEMM + running-min + candidate admission ----------------
// score s = ||c||^2 - 2*x.c (+bias). min_k s == min_k d2. Admit k with s <= min + MARGIN.
// MARGIN=16 >> 6-sigma bf16 dot error (~1.1) -> any fp32-argmin contender admitted.
__global__ __launch_bounds__(256, 3)
void gemm_select(const u16* __restrict__ xbf, const u16* __restrict__ cbf,
                 const float* __restrict__ c2, u32* __restrict__ cand_cnt,
                 u16* __restrict__ cand) {
    __shared__ u16 Alds[BM * NFEAT];   // 32 KB, XOR-swizzled rows
    __shared__ u16 Blds[BNC * BK];     // 16 KB, XOR-swizzled rows
    __shared__ u32 rmin[BM];           // packed (score|col) running min per point

    const int tid  = threadIdx.x;
    const int lane = tid & 63;
    const int wid  = tid >> 6;
    const int wm = wid >> 1, wn = wid & 1;    // 2x2 wave grid
    const int mtile = blockIdx.x;

    if (tid < BM) rmin[tid] = 0xFFFFFFFFu;

    // stage A once: 64 rows x 256 k bf16 (source pre-swizzled so LDS reads are conflict-free)
    {
        const char* xb = (const char*)xbf + (size_t)mtile * BM * (NFEAT * 2);
        #pragma unroll
        for (int t = 0; t < 8; ++t) {
            int L = (t * 256 + tid) * 16;
            int row = L >> 9;
            int inrow = L & 511;
            int src = inrow ^ ((row & 7) << 4);
            GL2LDS(xb + ((size_t)row << 9) + src, (char*)Alds + L);
        }
    }

    for (int chunk = 0; chunk < NCHUNK; ++chunk) {
        f32x4 acc[2][4];
        #pragma unroll
        for (int mf = 0; mf < 2; ++mf)
            #pragma unroll
            for (int nf = 0; nf < 4; ++nf) acc[mf][nf] = 0.0f;

        for (int ks = 0; ks < NFEAT / BK; ++ks) {
            __syncthreads();   // previous compute/admission done -> safe to overwrite Blds
            #pragma unroll
            for (int t = 0; t < 4; ++t) {   // stage B: 128 clusters x 64 k
                int L = (t * 256 + tid) * 16;
                int row = L >> 7;
                int inrow = L & 127;
                int src = inrow ^ ((row & 7) << 4);
                GL2LDS((const char*)cbf + ((size_t)(chunk * BNC + row) << 9) + (ks << 7) + src,
                       (char*)Blds + L);
            }
            __syncthreads();   // vmcnt(0) drain -> staged tiles visible

            #pragma unroll
            for (int kk = 0; kk < BK; kk += 32) {
                bf16x8 a[2], b[4];
                #pragma unroll
                for (int mf = 0; mf < 2; ++mf) {
                    int row = wm * 32 + mf * 16 + (lane & 15);
                    int kb = (ks * BK + kk + ((lane >> 4) << 3)) << 1;
                    a[mf] = *(const bf16x8*)((const char*)Alds + row * 512 + (kb ^ ((row & 7) << 4)));
                }
                #pragma unroll
                for (int nf = 0; nf < 4; ++nf) {
                    int row = wn * 64 + nf * 16 + (lane & 15);
                    int kb = (kk + ((lane >> 4) << 3)) << 1;
                    b[nf] = *(const bf16x8*)((const char*)Blds + row * 128 + (kb ^ ((row & 7) << 4)));
                }
                #pragma unroll
                for (int mf = 0; mf < 2; ++mf)
                    #pragma unroll
                    for (int nf = 0; nf < 4; ++nf)
                        acc[mf][nf] = __builtin_amdgcn_mfma_f32_16x16x32_bf16(
                            a[mf], b[nf], acc[mf][nf], 0, 0, 0);
            }
        }

        // ---- epilogue: per-point running min over this chunk's 128 clusters ----
        // C/D layout (16x16x32): col = lane&15, row = (lane>>4)*4 + reg
        const int colbase = chunk * BNC + wn * 64 + (lane & 15);
        float c2v[4];
        #pragma unroll
        for (int nf = 0; nf < 4; ++nf) c2v[nf] = c2[colbase + nf * 16];

        #pragma unroll
        for (int mf = 0; mf < 2; ++mf) {
            #pragma unroll
            for (int j = 0; j < 4; ++j) {
                u32 kmin = 0xFFFFFFFFu;
                #pragma unroll
                for (int nf = 0; nf < 4; ++nf) {
                    float s = c2v[nf] - 2.0f * acc[mf][nf][j] + SBIAS;  // biased positive
                    u32 key = (__float_as_uint(s) & 0xFFFFFC00u) | (u32)(colbase + nf * 16);
                    kmin = min(kmin, key);
                }
                #pragma unroll
                for (int m = 1; m < 16; m <<= 1)
                    kmin = min(kmin, (u32)__shfl_xor((int)kmin, m));
                if ((lane & 15) == 0) {
                    int rowl = wm * 32 + mf * 16 + ((lane >> 4) << 2) + j;
                    atomicMin(&rmin[rowl], kmin);
                }
            }
        }
        __syncthreads();
        // ---- admission: keep clusters within MARGIN of running min (superset of final) ----
        #pragma unroll
        for (int mf = 0; mf < 2; ++mf) {
            #pragma unroll
            for (int j = 0; j < 4; ++j) {
                int rowl = wm * 32 + mf * 16 + ((lane >> 4) << 2) + j;
                float thr = __uint_as_float(rmin[rowl] & 0xFFFFFC00u) + MARGIN;
                #pragma unroll
                for (int nf = 0; nf < 4; ++nf) {
                    float s = c2v[nf] - 2.0f * acc[mf][nf][j] + SBIAS;
                    if (s <= thr) {
                        int p = mtile * BM + rowl;
                        u32 pos = atomicAdd(&cand_cnt[p], 1u);
                        if (pos < CAND_CAP) cand[(size_t)p * CAND_CAP + pos] = (u16)(colbase + nf * 16);
                    }
                }
            }
        }
    }
}

// ---------------- K4: np-fp32-replicating refine (1 wave/point, 1 candidate/lane) ----------
// Labels must equal np.argmin over DISTANCES = sqrt(max(d2,0)) -- NOT over d2: fp32 sqrt
// collapses near-ties (window ~2*d*ulp ~ 2.1e-5 at d~11), and np.argmin then takes the
// FIRST index. R1/R7's bit-identical failures (absmax 122, different evaluators) pin the
// deciding flip on exactly this mechanism. So: d2 = (x2 + c2[k]) - 2*dot with dot =
// sequential-k fp32 FMA chain (BLAS sgemm microkernel order: one accumulator per C
// element, ascending k), c2/x2 = numpy npyv-pairwise (np_sq_sum256), final ops
// un-contracted; then compare (sqrtf(fmaxf(d2,0)), k) lexicographically.
// sqrtf is IEEE-correct (no fast-math) = np.sqrt.
__global__ void refine_np(const float* __restrict__ x, const float* __restrict__ centers,
                          const float* __restrict__ x2np, const float* __restrict__ c2np,
                          const u32* __restrict__ cand_cnt, const u16* __restrict__ cand,
                          float* __restrict__ out_mind, float* __restrict__ out_lab,
                          int* __restrict__ labels_i) {
    #pragma clang fp contract(off)
    const int lane = threadIdx.x & 63;
    const int wid  = threadIdx.x >> 6;
    const int p = blockIdx.x * 4 + wid;
    const u32 cnt = cand_cnt[p];
    const float4* xr = (const float4*)(x + (size_t)p * NFEAT);
    const float myx2 = x2np[p];
    float bestdi = 3.0e38f;
    int bestk = 0x7FFFFFFF;

    const bool full = (cnt > CAND_CAP);          // overflow fallback: scan all 1024
    const int iters = full ? (NCLUST / 64) : 1;
    for (int t = 0; t < iters; ++t) {
        int k = -1;
        if (full) k = t * 64 + lane;
        else if ((u32)lane < cnt) k = (int)cand[(size_t)p * CAND_CAP + lane];
        if (k >= 0) {
            const float4* cr = (const float4*)(centers + (size_t)k * NFEAT);
            float dot = 0.0f;
            #pragma unroll 16
            for (int j = 0; j < 64; ++j) {
                float4 xv = xr[j], cv = cr[j];
                dot = __builtin_fmaf(xv.x, cv.x, dot);
                dot = __builtin_fmaf(xv.y, cv.y, dot);
                dot = __builtin_fmaf(xv.z, cv.z, dot);
                dot = __builtin_fmaf(xv.w, cv.w, dot);
            }
            float d2 = (myx2 + c2np[k]) - 2.0f * dot;
            float di = sqrtf(fmaxf(d2, 0.0f));   // np: distances = sqrt(maximum(d2,0))
            if (di < bestdi || (di == bestdi && k < bestk)) { bestdi = di; bestk = k; }
        }
    }
    // wave-wide lexicographic (distance, k) min == np.argmin first-index semantics
    #pragma unroll
    for (int m = 1; m < 64; m <<= 1) {
        float od = __shfl_xor(bestdi, m);
        int   ok = __shfl_xor(bestk, m);
        if (od < bestdi || (od == bestdi && ok < bestk)) { bestdi = od; bestk = ok; }
    }
    if (lane == 0) {
        out_mind[p] = bestdi;
        out_lab[p]  = (float)bestk;
        labels_i[p] = bestk;
    }
}

// ---------------- K5: per-cluster mean (compact point list in LDS, coalesced row gather) ----
// Gather loop 4-way unrolled: 4 independent loads in flight per wave instead of 1.
__global__ void cluster_mean(const float* __restrict__ x, const int* __restrict__ labels_i,
                             const float* __restrict__ centers, float* __restrict__ outc) {
    __shared__ int list[8192];
    __shared__ int lcnt;
    const int k = blockIdx.x, t = threadIdx.x;   // 1024 blocks x 256 thr (thread = feature)
    float a0 = 0.0f, a1 = 0.0f, a2 = 0.0f, a3 = 0.0f;
    int total = 0;
    for (int base = 0; base < NPTS; base += 8192) {
        if (t == 0) lcnt = 0;
        __syncthreads();
        for (int i = t; i < 8192; i += 256) {
            int p = base + i;
            if (labels_i[p] == k) { int pos = atomicAdd(&lcnt, 1); list[pos] = p; }
        }
        __syncthreads();
        int n = lcnt;
        int i = 0;
        for (; i + 4 <= n; i += 4) {
            int p0 = list[i], p1 = list[i + 1], p2 = list[i + 2], p3 = list[i + 3];
            a0 += x[(size_t)p0 * NFEAT + t];
            a1 += x[(size_t)p1 * NFEAT + t];
            a2 += x[(size_t)p2 * NFEAT + t];
            a3 += x[(size_t)p3 * NFEAT + t];
        }
        for (; i < n; ++i) a0 += x[(size_t)list[i] * NFEAT + t];
        total += n;
        __syncthreads();
    }
    float acc = (a0 + a1) + (a2 + a3);
    outc[k * NFEAT + t] = (total > 0) ? (acc / (float)total) : centers[k * NFEAT + t];
}

extern "C" void kernel_launch(void* const* d_in, const int* in_sizes, int n_in,
                              void* d_out, int out_size, void* d_ws, size_t ws_size,
                              hipStream_t stream) {
    const float* x       = (const float*)d_in[0];
    const float* centers = (const float*)d_in[1];
    float* out_mind = (float*)d_out;           // [N]
    float* out_lab  = out_mind + NPTS;         // [N] labels as float
    float* out_cent = out_lab + NPTS;          // [K*D]

    char* w = (char*)d_ws;
    u16*   xbf      = (u16*)w;  w += (size_t)NPTS * NFEAT * 2;     // 64 MB
    u16*   cbf      = (u16*)w;  w += (size_t)NCLUST * NFEAT * 2;   // 0.5 MB
    float* c2np     = (float*)w; w += (size_t)NCLUST * 4;
    float* x2np     = (float*)w; w += (size_t)NPTS * 4;            // 0.5 MB
    u32*   cand_cnt = (u32*)w;  w += (size_t)NPTS * 4;             // 0.5 MB
    u16*   cand     = (u16*)w;  w += (size_t)NPTS * CAND_CAP * 2;  // 8 MB
    int*   labels_i = (int*)w;  w += (size_t)NPTS * 4;             // 0.5 MB

    hipMemsetAsync(cand_cnt, 0, (size_t)NPTS * 4, stream);
    prep_bf16<<<NPTS * NFEAT / 8 / 256, 256, 0, stream>>>(x, xbf);
    prep_bf16<<<NCLUST * NFEAT / 8 / 256, 256, 0, stream>>>(centers, cbf);
    np_row_sq<<<NPTS / 256, 256, 0, stream>>>(x, x2np, NPTS);
    np_row_sq<<<NCLUST / 256, 256, 0, stream>>>(centers, c2np, NCLUST);
    gemm_select<<<NPTS / BM, 256, 0, stream>>>(xbf, cbf, c2np, cand_cnt, cand);
    refine_np<<<NPTS / 4, 256, 0, stream>>>(x, centers, x2np, c2np, cand_cnt, cand,
                                            out_mind, out_lab, labels_i);
    cluster_mean<<<NCLUST, 256, 0, stream>>>(x, labels_i, centers, out_cent);
}